// Round 1
// baseline (272.658 us; speedup 1.0000x reference)
//
#include <hip/hip_runtime.h>
#include <stdint.h>

typedef __attribute__((ext_vector_type(4))) float f32x4;
typedef __attribute__((ext_vector_type(8))) _Float16 f16x8;
typedef __attribute__((ext_vector_type(8))) unsigned short u16x8;

#define HIDDEN 1024
#define SEQ 2048
#define NB 4

__device__ inline unsigned short f2h_bits(float f) {
    _Float16 h = (_Float16)f;
    return __builtin_bit_cast(unsigned short, h);
}

// C[M,N] = A[M,K] * Bt[N,K]^T (+bias). A row-major (lda), Bt row-major (ld = K).
// A is f32 (converted to fp16 during staging) or fp16 bits; C is fp16 bits or f32.
template<bool A_F32, bool OUT_F16, bool HAS_BIAS>
__global__ void gemm_bt(const void* __restrict__ Aptr,
                        const unsigned short* __restrict__ Bt,
                        const float* __restrict__ bias,
                        void* __restrict__ Cptr,
                        int M, int N, int K, int lda,
                        long long aBatch, long long bBatch, long long cBatch)
{
    (void)M;
    __shared__ unsigned short La[128][40];  // +8 pad: 80B row stride
    __shared__ unsigned short Lb[128][40];

    const int tid  = threadIdx.x;
    const int lane = tid & 63;
    const int wave = tid >> 6;
    const int wr = wave >> 1;   // wave row 0..1
    const int wc = wave & 1;    // wave col 0..1
    const int fr = lane & 15;
    const int fq = lane >> 4;
    const int ko = fq * 8;

    const long long bz = blockIdx.z;
    const int row0 = blockIdx.y * 128;
    const int col0 = blockIdx.x * 128;

    const float* Af = nullptr;
    const unsigned short* Ah = nullptr;
    if constexpr (A_F32) Af = (const float*)Aptr + bz * aBatch;
    else                 Ah = (const unsigned short*)Aptr + bz * aBatch;
    const unsigned short* Bb = Bt + bz * bBatch;

    f32x4 acc[4][4] = {};

    // staging: 512 chunks of 8 fp16 (16B); thread handles chunks tid and tid+256
    const int r0  = tid >> 2;          // rows 0..63
    const int r1  = r0 + 64;           // rows 64..127
    const int cc0 = (tid & 3) * 8;     // k-offset within tile

    for (int k0 = 0; k0 < K; k0 += 32) {
        if constexpr (A_F32) {
            const float* s0 = Af + (long long)(row0 + r0) * lda + k0 + cc0;
            const float* s1 = Af + (long long)(row0 + r1) * lda + k0 + cc0;
            float4 a0 = *(const float4*)s0, a1 = *(const float4*)(s0 + 4);
            float4 b0 = *(const float4*)s1, b1 = *(const float4*)(s1 + 4);
            u16x8 t0, t1;
            t0[0]=f2h_bits(a0.x); t0[1]=f2h_bits(a0.y); t0[2]=f2h_bits(a0.z); t0[3]=f2h_bits(a0.w);
            t0[4]=f2h_bits(a1.x); t0[5]=f2h_bits(a1.y); t0[6]=f2h_bits(a1.z); t0[7]=f2h_bits(a1.w);
            t1[0]=f2h_bits(b0.x); t1[1]=f2h_bits(b0.y); t1[2]=f2h_bits(b0.z); t1[3]=f2h_bits(b0.w);
            t1[4]=f2h_bits(b1.x); t1[5]=f2h_bits(b1.y); t1[6]=f2h_bits(b1.z); t1[7]=f2h_bits(b1.w);
            *(u16x8*)&La[r0][cc0] = t0;
            *(u16x8*)&La[r1][cc0] = t1;
        } else {
            *(u16x8*)&La[r0][cc0] = *(const u16x8*)(Ah + (long long)(row0 + r0) * lda + k0 + cc0);
            *(u16x8*)&La[r1][cc0] = *(const u16x8*)(Ah + (long long)(row0 + r1) * lda + k0 + cc0);
        }
        *(u16x8*)&Lb[r0][cc0] = *(const u16x8*)(Bb + (long long)(col0 + r0) * K + k0 + cc0);
        *(u16x8*)&Lb[r1][cc0] = *(const u16x8*)(Bb + (long long)(col0 + r1) * K + k0 + cc0);
        __syncthreads();

        f16x8 af[4], bfv[4];
        #pragma unroll
        for (int m = 0; m < 4; ++m)
            af[m] = *(const f16x8*)&La[wr*64 + m*16 + fr][ko];
        #pragma unroll
        for (int n = 0; n < 4; ++n)
            bfv[n] = *(const f16x8*)&Lb[wc*64 + n*16 + fr][ko];
        #pragma unroll
        for (int m = 0; m < 4; ++m)
            #pragma unroll
            for (int n = 0; n < 4; ++n)
                acc[m][n] = __builtin_amdgcn_mfma_f32_16x16x32_f16(af[m], bfv[n], acc[m][n], 0, 0, 0);
        __syncthreads();
    }

    // epilogue: C/D layout col=lane&15, row=(lane>>4)*4+i
    if constexpr (OUT_F16) {
        unsigned short* C = (unsigned short*)Cptr + bz * cBatch;
        #pragma unroll
        for (int m = 0; m < 4; ++m)
            #pragma unroll
            for (int n = 0; n < 4; ++n)
                #pragma unroll
                for (int i = 0; i < 4; ++i) {
                    int r = row0 + wr*64 + m*16 + fq*4 + i;
                    int c = col0 + wc*64 + n*16 + fr;
                    float val = acc[m][n][i];
                    if constexpr (HAS_BIAS) val += bias[c];
                    C[(long long)r * N + c] = f2h_bits(val);
                }
    } else {
        float* C = (float*)Cptr + bz * cBatch;
        #pragma unroll
        for (int m = 0; m < 4; ++m)
            #pragma unroll
            for (int n = 0; n < 4; ++n)
                #pragma unroll
                for (int i = 0; i < 4; ++i) {
                    int r = row0 + wr*64 + m*16 + fq*4 + i;
                    int c = col0 + wc*64 + n*16 + fr;
                    float val = acc[m][n][i];
                    if constexpr (HAS_BIAS) val += bias[c];
                    C[(long long)r * N + c] = val;
                }
    }
}

// out[C][R] = in[R][C], converting f32->fp16 bits if IN_F32, else copying fp16 bits.
template<bool IN_F32>
__global__ void transpose_cvt(const void* __restrict__ inPtr, unsigned short* __restrict__ out,
                              int R, int C, long long inBatch, long long outBatch)
{
    __shared__ unsigned short t[32][33];
    const long long bz = blockIdx.z;
    const int bx = blockIdx.x * 32;   // input col base
    const int by = blockIdx.y * 32;   // input row base
    const int xT = threadIdx.x, yT = threadIdx.y;  // block (32,8)

    #pragma unroll
    for (int i = 0; i < 32; i += 8) {
        if constexpr (IN_F32) {
            const float* in = (const float*)inPtr + bz * inBatch;
            t[yT + i][xT] = f2h_bits(in[(long long)(by + yT + i) * C + bx + xT]);
        } else {
            const unsigned short* in = (const unsigned short*)inPtr + bz * inBatch;
            t[yT + i][xT] = in[(long long)(by + yT + i) * C + bx + xT];
        }
    }
    __syncthreads();
    unsigned short* o = out + bz * outBatch;
    #pragma unroll
    for (int i = 0; i < 32; i += 8)
        o[(long long)(bx + yT + i) * R + by + xT] = t[xT][yT + i];
}

// One block (256 threads) per row of 2048 f32 scores.
// Writes P (fp16 bits) in place over the first half of the same row.
__global__ __launch_bounds__(256) void softmax_inplace(float* __restrict__ S)
{
    const int tid = threadIdx.x;
    float* row = S + (long long)blockIdx.x * SEQ;
    float4 a = ((const float4*)row)[tid];
    float4 b = ((const float4*)row)[tid + 256];
    float vv[8] = {a.x, a.y, a.z, a.w, b.x, b.y, b.z, b.w};

    float mx = vv[0];
    #pragma unroll
    for (int j = 1; j < 8; ++j) mx = fmaxf(mx, vv[j]);
    #pragma unroll
    for (int o = 32; o > 0; o >>= 1) mx = fmaxf(mx, __shfl_xor(mx, o));
    __shared__ float redm[4], reds[4];
    if ((tid & 63) == 0) redm[tid >> 6] = mx;
    __syncthreads();
    mx = fmaxf(fmaxf(redm[0], redm[1]), fmaxf(redm[2], redm[3]));

    float ev[8], sum = 0.f;
    #pragma unroll
    for (int j = 0; j < 8; ++j) { ev[j] = __expf(vv[j] - mx); sum += ev[j]; }
    #pragma unroll
    for (int o = 32; o > 0; o >>= 1) sum += __shfl_xor(sum, o);
    if ((tid & 63) == 0) reds[tid >> 6] = sum;
    __syncthreads();
    sum = reds[0] + reds[1] + reds[2] + reds[3];
    float inv = 1.0f / sum;

    unsigned short* rb = (unsigned short*)row;
    ushort4 o0, o1;
    o0.x = f2h_bits(ev[0] * inv); o0.y = f2h_bits(ev[1] * inv);
    o0.z = f2h_bits(ev[2] * inv); o0.w = f2h_bits(ev[3] * inv);
    o1.x = f2h_bits(ev[4] * inv); o1.y = f2h_bits(ev[5] * inv);
    o1.z = f2h_bits(ev[6] * inv); o1.w = f2h_bits(ev[7] * inv);
    // all loads completed before the barriers above; safe to overwrite
    *(ushort4*)&rb[(long long)tid * 4] = o0;
    *(ushort4*)&rb[((long long)tid + 256) * 4] = o1;
}

extern "C" void kernel_launch(void* const* d_in, const int* in_sizes, int n_in,
                              void* d_out, int out_size, void* d_ws, size_t ws_size,
                              hipStream_t stream)
{
    (void)in_sizes; (void)n_in; (void)out_size;
    const float* x  = (const float*)d_in[0];
    const float* Wq = (const float*)d_in[1];
    const float* bq = (const float*)d_in[2];
    const float* Wk = (const float*)d_in[3];
    const float* bk = (const float*)d_in[4];
    const float* Wv = (const float*)d_in[5];
    const float* bv = (const float*)d_in[6];
    float* out = (float*)d_out;

    char* ws = (char*)d_ws;
    const long long MTOT = (long long)NB * SEQ;  // 8192
    size_t off = 0;
    auto take = [&](size_t b){ size_t p = off; off += (b + 255) & ~(size_t)255; return p; };
    unsigned short* q    = (unsigned short*)(ws + take((size_t)MTOT * HIDDEN * 2));
    unsigned short* kmat = (unsigned short*)(ws + take((size_t)MTOT * HIDDEN * 2));
    unsigned short* vmat = (unsigned short*)(ws + take((size_t)MTOT * HIDDEN * 2));
    unsigned short* vt   = (unsigned short*)(ws + take((size_t)MTOT * HIDDEN * 2));
    unsigned short* wt   = (unsigned short*)(ws + take((size_t)3 * HIDDEN * HIDDEN * 2));
    const size_t sPer = (size_t)SEQ * SEQ * 4;  // one batch of f32 scores
    size_t rem = ws_size > off ? ws_size - off : 0;
    int ngrp = (int)(rem / sPer);
    if (ngrp > NB) ngrp = NB;
    if (ngrp < 1) ngrp = 1;
    float* S = (float*)(ws + off);

    dim3 tb(32, 8);
    // W^T (fp16) for the three projections
    transpose_cvt<true><<<dim3(HIDDEN/32, HIDDEN/32, 1), tb, 0, stream>>>(Wq, wt,                     HIDDEN, HIDDEN, 0, 0);
    transpose_cvt<true><<<dim3(HIDDEN/32, HIDDEN/32, 1), tb, 0, stream>>>(Wk, wt +   HIDDEN*HIDDEN,   HIDDEN, HIDDEN, 0, 0);
    transpose_cvt<true><<<dim3(HIDDEN/32, HIDDEN/32, 1), tb, 0, stream>>>(Wv, wt + 2*HIDDEN*HIDDEN,   HIDDEN, HIDDEN, 0, 0);

    // QKV projections: [8192,1024] = x[8192,1024] @ W + b, fp16 out
    dim3 gq(HIDDEN/128, (unsigned)(MTOT/128), 1);
    gemm_bt<true,true,true><<<gq, 256, 0, stream>>>(x, wt,                   bq, q,    (int)MTOT, HIDDEN, HIDDEN, HIDDEN, 0, 0, 0);
    gemm_bt<true,true,true><<<gq, 256, 0, stream>>>(x, wt +   HIDDEN*HIDDEN, bk, kmat, (int)MTOT, HIDDEN, HIDDEN, HIDDEN, 0, 0, 0);
    gemm_bt<true,true,true><<<gq, 256, 0, stream>>>(x, wt + 2*HIDDEN*HIDDEN, bv, vmat, (int)MTOT, HIDDEN, HIDDEN, HIDDEN, 0, 0, 0);

    // v^T per batch: [1024,2048]
    transpose_cvt<false><<<dim3(HIDDEN/32, SEQ/32, NB), tb, 0, stream>>>(
        vmat, vt, SEQ, HIDDEN, (long long)SEQ*HIDDEN, (long long)SEQ*HIDDEN);

    for (int b0 = 0; b0 < NB; b0 += ngrp) {
        int nb = (NB - b0 < ngrp) ? NB - b0 : ngrp;
        // S = q @ k^T  (f32 out)
        gemm_bt<false,false,false><<<dim3(SEQ/128, SEQ/128, nb), 256, 0, stream>>>(
            q + (long long)b0*SEQ*HIDDEN, kmat + (long long)b0*SEQ*HIDDEN, nullptr, S,
            SEQ, SEQ, HIDDEN, HIDDEN,
            (long long)SEQ*HIDDEN, (long long)SEQ*HIDDEN, (long long)SEQ*SEQ);
        // row softmax, P fp16 written in place (row stride becomes 4096 fp16 elems)
        softmax_inplace<<<dim3(nb * SEQ), 256, 0, stream>>>(S);
        // O = P @ v  (f32 out straight to d_out)
        gemm_bt<false,false,false><<<dim3(HIDDEN/128, SEQ/128, nb), 256, 0, stream>>>(
            S, vt + (long long)b0*HIDDEN*SEQ, nullptr, out + (long long)b0*SEQ*HIDDEN,
            SEQ, HIDDEN, SEQ, 2*SEQ,
            (long long)SEQ*2*SEQ, (long long)HIDDEN*SEQ, (long long)SEQ*HIDDEN);
    }
}

// Round 2
// 247.640 us; speedup vs baseline: 1.1010x; 1.1010x over previous
//
#include <hip/hip_runtime.h>
#include <stdint.h>

typedef __attribute__((ext_vector_type(4))) float f32x4;
typedef __attribute__((ext_vector_type(8))) _Float16 f16x8;

#define HIDDEN 1024
#define SEQ 2048
#define NB 4

__device__ inline unsigned short f2h_bits(float f) {
    _Float16 h = (_Float16)f;
    return __builtin_bit_cast(unsigned short, h);
}

__device__ inline void gload16(const void* g, void* l) {
    __builtin_amdgcn_global_load_lds(
        (const __attribute__((address_space(1))) unsigned int*)g,
        (__attribute__((address_space(3))) unsigned int*)l,
        16, 0, 0);
}

// C[M,N] = A[M,K] @ Bt[N,K]^T (+bias). All fp16 inputs, f32 accum.
// BM in {64,128}; BN fixed 128. 256 threads (4 waves).
// BIAS_MODE: 0 none, 1 bias[col], 2 bias[row].
template<int BM, int BIAS_MODE, bool OUT_F16>
__global__ __launch_bounds__(256) void gemm_lds(
    const unsigned short* __restrict__ A, int lda,
    const unsigned short* __restrict__ Bt, int ldb,
    const float* __restrict__ bias,
    void* __restrict__ Cptr, int ldc, int K,
    long long aBatch, long long bBatch, long long cBatch)
{
    constexpr int WAVES_N = (BM == 128) ? 2 : 4;  // wave grid: (BM/64) x WAVES_N
    constexpr int WN = 128 / WAVES_N;             // wave col extent: 64 or 32
    constexpr int NR = WN / 16;                   // n-frags per wave: 4 or 2
    constexpr int AI = BM / 64;                   // A-stage issues per wave

    __shared__ unsigned short La[BM][32];
    __shared__ unsigned short Lb[128][32];

    const int tid  = threadIdx.x;
    const int lane = tid & 63;
    const int wave = tid >> 6;
    const int wr = wave / WAVES_N;
    const int wc = wave % WAVES_N;
    const int fr = lane & 15;
    const int fq = lane >> 4;
    const int ko = fq * 8;

    const long long bz = blockIdx.z;
    const int row0 = blockIdx.y * BM;
    const int col0 = blockIdx.x * 128;

    const unsigned short* Ab = A + bz * aBatch;
    const unsigned short* Bb = Bt + bz * bBatch;

    f32x4 acc[4][NR] = {};

    // staging geometry: 16B chunk c covers row c>>2, cols ((c&3)*8..+8) of a [*][32] tile
    for (int k0 = 0; k0 < K; k0 += 32) {
        #pragma unroll
        for (int i = 0; i < AI; ++i) {
            int chunk = (wave * AI + i) * 64 + lane;
            int r = chunk >> 2, c8 = (chunk & 3) * 8;
            gload16(Ab + (long long)(row0 + r) * lda + k0 + c8,
                    (char*)&La[0][0] + (wave * AI + i) * 1024);
        }
        #pragma unroll
        for (int i = 0; i < 2; ++i) {
            int chunk = (wave * 2 + i) * 64 + lane;
            int r = chunk >> 2, c8 = (chunk & 3) * 8;
            gload16(Bb + (long long)(col0 + r) * ldb + k0 + c8,
                    (char*)&Lb[0][0] + (wave * 2 + i) * 1024);
        }
        __syncthreads();   // compiler emits vmcnt(0) drain before barrier

        f16x8 af[4], bf[NR];
        #pragma unroll
        for (int m = 0; m < 4; ++m)
            af[m] = *(const f16x8*)&La[wr * 64 + m * 16 + fr][ko];
        #pragma unroll
        for (int n = 0; n < NR; ++n)
            bf[n] = *(const f16x8*)&Lb[wc * WN + n * 16 + fr][ko];
        #pragma unroll
        for (int m = 0; m < 4; ++m)
            #pragma unroll
            for (int n = 0; n < NR; ++n)
                acc[m][n] = __builtin_amdgcn_mfma_f32_16x16x32_f16(af[m], bf[n], acc[m][n], 0, 0, 0);
        __syncthreads();
    }

    // C/D layout: col = lane&15, row = (lane>>4)*4 + i
    #pragma unroll
    for (int m = 0; m < 4; ++m)
        #pragma unroll
        for (int n = 0; n < NR; ++n)
            #pragma unroll
            for (int i = 0; i < 4; ++i) {
                int r = row0 + wr * 64 + m * 16 + fq * 4 + i;
                int c = col0 + wc * WN + n * 16 + fr;
                float val = acc[m][n][i];
                if constexpr (BIAS_MODE == 1) val += bias[c];
                if constexpr (BIAS_MODE == 2) val += bias[r];
                if constexpr (OUT_F16)
                    ((unsigned short*)Cptr + bz * cBatch)[(long long)r * ldc + c] = f2h_bits(val);
                else
                    ((float*)Cptr + bz * cBatch)[(long long)r * ldc + c] = val;
            }
}

// x (f32) -> fp16 bits, 8 elems/thread
__global__ __launch_bounds__(256) void cvt_f32_f16(const float* __restrict__ in,
                                                   unsigned short* __restrict__ out, int n8)
{
    int i = blockIdx.x * blockDim.x + threadIdx.x;
    if (i >= n8) return;
    const float4* p = (const float4*)in + (long long)i * 2;
    float4 a = p[0], b = p[1];
    ushort4 o0, o1;
    o0.x = f2h_bits(a.x); o0.y = f2h_bits(a.y); o0.z = f2h_bits(a.z); o0.w = f2h_bits(a.w);
    o1.x = f2h_bits(b.x); o1.y = f2h_bits(b.y); o1.z = f2h_bits(b.z); o1.w = f2h_bits(b.w);
    ushort4* o = (ushort4*)out + (long long)i * 2;
    o[0] = o0; o[1] = o1;
}

// out[c][r] = (fp16) in[r][c], square-ish f32 input, ld == C in, ld == R out
__global__ void transpose_cvt(const float* __restrict__ in, unsigned short* __restrict__ out,
                              int R, int C)
{
    __shared__ unsigned short t[32][33];
    const int bx = blockIdx.x * 32;
    const int by = blockIdx.y * 32;
    const int xT = threadIdx.x, yT = threadIdx.y;  // block (32,8)
    #pragma unroll
    for (int i = 0; i < 32; i += 8)
        t[yT + i][xT] = f2h_bits(in[(long long)(by + yT + i) * C + bx + xT]);
    __syncthreads();
    #pragma unroll
    for (int i = 0; i < 32; i += 8)
        out[(long long)(bx + yT + i) * R + by + xT] = t[xT][yT + i];
}

__global__ void concat_bias(const float* __restrict__ bq, const float* __restrict__ bk,
                            float* __restrict__ cb)
{
    int i = threadIdx.x;  // 1024 threads
    cb[i] = bq[i];
    cb[HIDDEN + i] = bk[i];
}

// One block (256 threads) per row of 2048 f32 scores.
// Writes P (fp16 bits) in place over the first half of the same row.
__global__ __launch_bounds__(256) void softmax_inplace(float* __restrict__ S)
{
    const int tid = threadIdx.x;
    float* row = S + (long long)blockIdx.x * SEQ;
    float4 a = ((const float4*)row)[tid];
    float4 b = ((const float4*)row)[tid + 256];
    float vv[8] = {a.x, a.y, a.z, a.w, b.x, b.y, b.z, b.w};

    float mx = vv[0];
    #pragma unroll
    for (int j = 1; j < 8; ++j) mx = fmaxf(mx, vv[j]);
    #pragma unroll
    for (int o = 32; o > 0; o >>= 1) mx = fmaxf(mx, __shfl_xor(mx, o));
    __shared__ float redm[4], reds[4];
    if ((tid & 63) == 0) redm[tid >> 6] = mx;
    __syncthreads();
    mx = fmaxf(fmaxf(redm[0], redm[1]), fmaxf(redm[2], redm[3]));

    float ev[8], sum = 0.f;
    #pragma unroll
    for (int j = 0; j < 8; ++j) { ev[j] = __expf(vv[j] - mx); sum += ev[j]; }
    #pragma unroll
    for (int o = 32; o > 0; o >>= 1) sum += __shfl_xor(sum, o);
    if ((tid & 63) == 0) reds[tid >> 6] = sum;
    __syncthreads();
    sum = reds[0] + reds[1] + reds[2] + reds[3];
    float inv = 1.0f / sum;

    unsigned short* rb = (unsigned short*)row;
    ushort4 o0, o1;
    o0.x = f2h_bits(ev[0] * inv); o0.y = f2h_bits(ev[1] * inv);
    o0.z = f2h_bits(ev[2] * inv); o0.w = f2h_bits(ev[3] * inv);
    o1.x = f2h_bits(ev[4] * inv); o1.y = f2h_bits(ev[5] * inv);
    o1.z = f2h_bits(ev[6] * inv); o1.w = f2h_bits(ev[7] * inv);
    // all loads consumed before the barriers above; safe to overwrite
    *(ushort4*)&rb[(long long)tid * 4] = o0;
    *(ushort4*)&rb[((long long)tid + 256) * 4] = o1;
}

extern "C" void kernel_launch(void* const* d_in, const int* in_sizes, int n_in,
                              void* d_out, int out_size, void* d_ws, size_t ws_size,
                              hipStream_t stream)
{
    (void)in_sizes; (void)n_in; (void)out_size;
    const float* x  = (const float*)d_in[0];
    const float* Wq = (const float*)d_in[1];
    const float* bq = (const float*)d_in[2];
    const float* Wk = (const float*)d_in[3];
    const float* bk = (const float*)d_in[4];
    const float* Wv = (const float*)d_in[5];
    const float* bv = (const float*)d_in[6];
    float* out = (float*)d_out;

    char* ws = (char*)d_ws;
    const long long MTOT = (long long)NB * SEQ;  // 8192
    size_t off = 0;
    auto take = [&](size_t b){ size_t p = off; off += (b + 255) & ~(size_t)255; return p; };

    // fixed-footprint buffers (~54.3 MB)
    unsigned short* qk  = (unsigned short*)(ws + take((size_t)MTOT * 2 * HIDDEN * 2)); // [8192][2048] fp16
    unsigned short* vtC = (unsigned short*)(ws + take((size_t)HIDDEN * MTOT * 2));     // [1024][8192] fp16
    unsigned short* wt  = (unsigned short*)(ws + take((size_t)3 * HIDDEN * HIDDEN * 2));
    float*          cb  = (float*)(ws + take((size_t)2 * HIDDEN * 4));

    // S region: xh (16 MB) lives here only until the vt-gemm completes; S reuses it after.
    size_t sOff = off;
    unsigned short* xh = (unsigned short*)(ws + sOff);
    float*          S  = (float*)(ws + sOff);
    const size_t sPer = (size_t)SEQ * SEQ * 4;
    size_t rem = ws_size > sOff ? ws_size - sOff : 0;
    int ngrp = (int)(rem / sPer);
    if (ngrp > NB) ngrp = NB;
    if (ngrp < 1) ngrp = 1;

    // x -> fp16
    {
        int n8 = (int)(MTOT * HIDDEN / 8);
        cvt_f32_f16<<<dim3((n8 + 255) / 256), 256, 0, stream>>>(x, xh, n8);
    }
    // W^T (fp16): wt rows = output feature, cols = input feature
    dim3 tb(32, 8), tg(HIDDEN / 32, HIDDEN / 32);
    transpose_cvt<<<tg, tb, 0, stream>>>(Wq, wt,                     HIDDEN, HIDDEN);
    transpose_cvt<<<tg, tb, 0, stream>>>(Wk, wt +   HIDDEN * HIDDEN, HIDDEN, HIDDEN);
    transpose_cvt<<<tg, tb, 0, stream>>>(Wv, wt + 2 * HIDDEN * HIDDEN, HIDDEN, HIDDEN);
    concat_bias<<<1, 1024, 0, stream>>>(bq, bk, cb);

    // qk[8192][2048] = xh @ [Wq|Wk] + [bq|bk]
    gemm_lds<128, 1, true><<<dim3(2048 / 128, (unsigned)(MTOT / 128), 1), 256, 0, stream>>>(
        xh, HIDDEN, wt, HIDDEN, cb, qk, 2048, HIDDEN, 0, 0, 0);

    // vtC[1024][8192] = Wv^T @ xh^T + bv (row bias): vt[e][j] = sum_i xh[j][i]*Wv[i][e] + bv[e]
    gemm_lds<128, 2, true><<<dim3((unsigned)(MTOT / 128), HIDDEN / 128, 1), 256, 0, stream>>>(
        wt + 2 * HIDDEN * HIDDEN, HIDDEN, xh, HIDDEN, bv, vtC, (int)MTOT, HIDDEN, 0, 0, 0);

    for (int b0 = 0; b0 < NB; b0 += ngrp) {
        int nb = (NB - b0 < ngrp) ? NB - b0 : ngrp;
        const unsigned short* q  = qk + (long long)b0 * SEQ * 2048;
        const unsigned short* km = q + HIDDEN;
        // S = q @ k^T  (f32)
        if (nb == 1)
            gemm_lds<64, 0, false><<<dim3(SEQ / 128, SEQ / 64, 1), 256, 0, stream>>>(
                q, 2048, km, 2048, nullptr, S, SEQ, HIDDEN, 0, 0, 0);
        else
            gemm_lds<128, 0, false><<<dim3(SEQ / 128, SEQ / 128, nb), 256, 0, stream>>>(
                q, 2048, km, 2048, nullptr, S, SEQ, HIDDEN,
                (long long)SEQ * 2048, (long long)SEQ * 2048, (long long)SEQ * SEQ);
        // softmax rows, P fp16 in place (row stride becomes 4096 halfs)
        softmax_inplace<<<dim3(nb * SEQ), 256, 0, stream>>>(S);
        // O = P @ v = P @ vtC^T  (f32 straight to d_out)
        const unsigned short* P = (const unsigned short*)S;
        const unsigned short* Bv = vtC + (long long)b0 * SEQ;
        float* Ob = out + (long long)b0 * SEQ * HIDDEN;
        if (nb == 1)
            gemm_lds<64, 0, false><<<dim3(HIDDEN / 128, SEQ / 64, 1), 256, 0, stream>>>(
                P, 2 * SEQ, Bv, (int)MTOT, nullptr, Ob, HIDDEN, SEQ, 0, 0, 0);
        else
            gemm_lds<128, 0, false><<<dim3(HIDDEN / 128, SEQ / 128, nb), 256, 0, stream>>>(
                P, 2 * SEQ, Bv, (int)MTOT, nullptr, Ob, HIDDEN, SEQ,
                (long long)SEQ * 2 * SEQ, (long long)SEQ, (long long)SEQ * HIDDEN);
    }
}